// Round 19
// baseline (106.330 us; speedup 1.0000x reference)
//
#include <hip/hip_runtime.h>
#include <hip/hip_bf16.h>
#include <math.h>

#define S_LEN 4096
#define EMB   1024
#define HEAD  128

typedef short bf16x8 __attribute__((ext_vector_type(8)));
typedef short s16x4  __attribute__((ext_vector_type(4)));
typedef float f32x4  __attribute__((ext_vector_type(4)));
typedef unsigned u32x2 __attribute__((ext_vector_type(2)));
typedef unsigned u32x4 __attribute__((ext_vector_type(4)));

static __device__ __forceinline__ short f2bf(float x){
  unsigned u = __builtin_bit_cast(unsigned, x);
  u += 0x7fffu + ((u >> 16) & 1u);
  return (short)(u >> 16);
}
static __device__ __forceinline__ float bf2f(short s){
  unsigned u = ((unsigned)(unsigned short)s) << 16;
  return __builtin_bit_cast(float, u);
}
// packed f32x2 -> bf16x2 (gfx950 v_cvt_pk_bf16_f32)
static __device__ __forceinline__ unsigned cvtpk(float a, float b){
  unsigned r;
  asm("v_cvt_pk_bf16_f32 %0, %1, %2" : "=v"(r) : "v"(a), "v"(b));
  return r;
}
static __device__ __forceinline__ f32x4 mfma16(bf16x8 a, bf16x8 b, f32x4 c){
  return __builtin_amdgcn_mfma_f32_16x16x32_bf16(a, b, c, 0, 0, 0);
}
static __device__ __forceinline__ void gload16(const void* g, void* l){
  __builtin_amdgcn_global_load_lds((const __attribute__((address_space(1))) unsigned*)g,
                                   (__attribute__((address_space(3))) unsigned*)l, 16, 0, 0);
}

// ---------------------------------------------------------------------------
// Kernel 0: WT_cat[384][1024] bf16 (transposed). Q cols pre-scaled by
// 1/sqrt(128)*log2(e) so attn uses exp2 (round-14 verified).
// ---------------------------------------------------------------------------
__global__ void prep_w(const float* __restrict__ Wq, const float* __restrict__ bq,
                       const float* __restrict__ Wk, const float* __restrict__ bk,
                       const float* __restrict__ Wv, const float* __restrict__ bv,
                       short* __restrict__ WT, float* __restrict__ bias){
  const float QS = 0.08838834764831845f * 1.4426950408889634f;
  int idx = blockIdx.x * 256 + threadIdx.x;
  int nc  = idx >> 10;
  int k   = idx & 1023;
  int mat = nc >> 7;
  int n   = nc & 127;
  const float* W = (mat == 0) ? Wq : (mat == 1) ? Wk : Wv;
  float s = (mat == 0) ? QS : 1.0f;
  WT[idx] = f2bf(W[k * HEAD + n] * s);
  if (idx < 384){
    int m2 = idx >> 7, n2 = idx & 127;
    const float* bsrc = (m2 == 0) ? bq : (m2 == 1) ? bk : bv;
    float s2 = (m2 == 0) ? QS : 1.0f;
    bias[idx] = bsrc[n2] * s2;
  }
}

// ---------------------------------------------------------------------------
// Kernel 1: fused QKV projection, 1024 threads, cvt_pk A-frags (r18 verified).
// ---------------------------------------------------------------------------
__global__ __launch_bounds__(1024) void qkv_proj(const float* __restrict__ x,
    const short* __restrict__ WT, const float* __restrict__ bias,
    short* __restrict__ Qo, short* __restrict__ Ko, short* __restrict__ VTo){
  __shared__ __align__(16) short Sm[2][32768];   // per buf: W 24576sh + X 8192sh

  const int tid = threadIdx.x;
  const int wave = tid >> 6, lane = tid & 63, lr = lane & 15, hg = lane >> 4;
  const int wrg = wave >> 3, cg = wave & 7, fbase = cg * 3;
  const int row0 = blockIdx.x * 64;

  const f32x4 zero = {0.f, 0.f, 0.f, 0.f};
  f32x4 acc[2][3];
  #pragma unroll
  for (int rf = 0; rf < 2; ++rf)
    #pragma unroll
    for (int f = 0; f < 3; ++f) acc[rf][f] = zero;

#define WL(buf) (&Sm[buf][0])
#define XL(buf) ((float*)&Sm[buf][24576])

#define QKV_STAGE(buf, k0)                                                         \
  {                                                                                \
    _Pragma("unroll")                                                              \
    for (int s = 0; s < 3; ++s){                                                   \
      int slot = s * 16 + wave;                                                    \
      int ff = slot >> 1, ks = slot & 1;                                           \
      gload16(WT + (size_t)(ff * 16 + lr) * 1024 + (k0) + ks * 32 + hg * 8,        \
              WL(buf) + slot * 512);                                               \
    }                                                                              \
    {                                                                              \
      int rr = wave * 4 + hg;                                                      \
      int cs = lr ^ (rr & 15);                                                     \
      gload16(x + (size_t)(row0 + rr) * 1024 + (k0) + cs * 4,                      \
              XL(buf) + wave * 256);                                               \
    }                                                                              \
  }

  QKV_STAGE(0, 0)

  int cur = 0;
  for (int t = 0; t < 16; ++t){
    if (t < 15){
      QKV_STAGE(cur ^ 1, (t + 1) * 64)
      asm volatile("s_waitcnt vmcnt(4)" ::: "memory");
    } else {
      asm volatile("s_waitcnt vmcnt(0)" ::: "memory");
    }
    __builtin_amdgcn_s_barrier();
    asm volatile("" ::: "memory");

    bf16x8 a[2][2];
    #pragma unroll
    for (int rf = 0; rf < 2; ++rf){
      const int xr = wrg * 32 + rf * 16 + lr;
      #pragma unroll
      for (int ks = 0; ks < 2; ++ks){
        int s0 = ks * 8 + hg * 2;
        f32x4 xa = *(const f32x4*)&XL(cur)[xr * 64 + ((s0 ^ lr) << 2)];
        f32x4 xb = *(const f32x4*)&XL(cur)[xr * 64 + (((s0 + 1) ^ lr) << 2)];
        u32x4 pk = { cvtpk(xa[0], xa[1]), cvtpk(xa[2], xa[3]),
                     cvtpk(xb[0], xb[1]), cvtpk(xb[2], xb[3]) };
        a[rf][ks] = __builtin_bit_cast(bf16x8, pk);
      }
    }
    __builtin_amdgcn_s_setprio(1);
    #pragma unroll
    for (int fi = 0; fi < 3; ++fi){
      #pragma unroll
      for (int ks = 0; ks < 2; ++ks){
        bf16x8 bfr = *(const bf16x8*)&WL(cur)[((fbase + fi) * 2 + ks) * 512 + lane * 8];
        acc[0][fi] = mfma16(a[0][ks], bfr, acc[0][fi]);
        acc[1][fi] = mfma16(a[1][ks], bfr, acc[1][fi]);
      }
    }
    __builtin_amdgcn_s_setprio(0);
    asm volatile("" ::: "memory");
    __builtin_amdgcn_s_barrier();
    cur ^= 1;
  }

  short* Vb = &Sm[0][0];   // 128 x 72 pitch bounce (aliases W buf, loop done)
  #pragma unroll
  for (int rf = 0; rf < 2; ++rf){
    #pragma unroll
    for (int fi = 0; fi < 3; ++fi){
      int f = fbase + fi;
      float bb = bias[f * 16 + lr];
      int rloc = wrg * 32 + rf * 16 + hg * 4;
      if (f < 16){
        short* dst = (f < 8) ? Qo : Ko;
        int col = (f & 7) * 16 + lr;
        #pragma unroll
        for (int r = 0; r < 4; ++r)
          dst[(size_t)(row0 + rloc + r) * HEAD + col] = f2bf(acc[rf][fi][r] + bb);
      } else {
        int vcol = (f - 16) * 16 + lr;
        #pragma unroll
        for (int r = 0; r < 4; ++r)
          Vb[vcol * 72 + rloc + r] = f2bf(acc[rf][fi][r] + bb);
      }
    }
  }
  __syncthreads();
  {
    int vcol = tid >> 3, sq = tid & 7;
    bf16x8 v = *(const bf16x8*)&Vb[vcol * 72 + sq * 8];
    int bb2 = row0 >> 12, ss = row0 & 4095;
    *(bf16x8*)(VTo + ((size_t)(bb2 * HEAD + vcol)) * S_LEN + ss + sq * 8) = v;
  }
}

// ---------------------------------------------------------------------------
// Kernel 2: split-KV causal flash. 4 waves x 32 q-rows, chunk 512,
// KV STEP 64 (was 32): halves barrier-steps, 64 MFMA/wave-step. K/V each
// 16 slots x 1KB per buffer, dbuf (64KB); per-wave P buffer [16][68]
// reused sequentially across q-sets (8.7KB). Fixed-max exp2 softmax,
// cvt_pk P-pack. Item maps as r15/r18 (ns now 8/6/4/2).
// ---------------------------------------------------------------------------
#define PPS 68

__global__ __launch_bounds__(256) void attn(const short* __restrict__ Q,
    const short* __restrict__ K, const short* __restrict__ VT,
    short* __restrict__ Opart, float* __restrict__ Dn){
  __shared__ __align__(16) short Kl[2][8192];
  __shared__ __align__(16) short Vl[2][8192];
  __shared__ __align__(16) short Pl[4][16 * PPS];

  const int tid = threadIdx.x;
  const int wave = tid >> 6, lane = tid & 63, lr = lane & 15, hg = lane >> 4;
  const int b = blockIdx.x;
  const int i = blockIdx.y;     // 0..143, heavy-first

  int t, c, ns;
  if (i < 120){
    int acc2 = 0; t = 0; c = 0;
    #pragma unroll
    for (int tt = 0; tt < 32; ++tt){
      int nf = (tt >> 2) + ((tt & 3) == 3);
      if (i >= acc2 && i < acc2 + nf){ t = tt; c = i - acc2; }
      acc2 += nf;
    }
    ns = 8;
  } else if (i < 128){ int k = i - 120; t = 4 * k + 2; c = k; ns = 6; }
  else if (i < 136)  { int k = i - 128; t = 4 * k + 1; c = k; ns = 4; }
  else               { int k = i - 136; t = 4 * k;     c = k; ns = 2; }

  const int qt0  = t * 128;
  const int kvlo = c << 9;

  const short* Qg = Q  + ((size_t)b * S_LEN + qt0 + wave * 32) * HEAD;
  const short* Kg = K  + (size_t)b * S_LEN * HEAD;
  const short* Vg = VT + (size_t)b * HEAD * S_LEN;

  bf16x8 qf[2][4];
  #pragma unroll
  for (int qs = 0; qs < 2; ++qs)
    #pragma unroll
    for (int sl = 0; sl < 4; ++sl)
      qf[qs][sl] = *(const bf16x8*)(Qg + (size_t)(qs * 16 + lr) * HEAD + sl * 32 + hg * 8);

  // wave w stages K slots {4w..4w+3} and V slots {4w..4w+3}; 8 gloads/wave.
  // K slot s: rows j0+(s>>2)*16, d cols (s&3)*32. V slot s<8: d-block s,
  // kv j0..j0+31; s>=8: d-block s-8, kv j0+32..j0+63.
#define ATTN_STAGE(buf, j0)                                                        \
  {                                                                                \
    _Pragma("unroll")                                                              \
    for (int q = 0; q < 4; ++q){                                                   \
      int s = wave * 4 + q;                                                        \
      gload16(Kg + (size_t)((j0) + (s >> 2) * 16 + lr) * HEAD + (s & 3) * 32 + hg * 8, \
              &Kl[buf][s * 512]);                                                  \
    }                                                                              \
    _Pragma("unroll")                                                              \
    for (int q = 0; q < 4; ++q){                                                   \
      int s = wave * 4 + q;                                                        \
      int db = (s < 8) ? s : s - 8;                                                \
      int ko = (s < 8) ? 0 : 32;                                                   \
      gload16(Vg + (size_t)(db * 16 + lr) * S_LEN + (j0) + ko + hg * 8,            \
              &Vl[buf][s * 512]);                                                  \
    }                                                                              \
  }

  ATTN_STAGE(0, kvlo)

  const f32x4 zero = {0.f, 0.f, 0.f, 0.f};
  f32x4 acc[8][2];
  #pragma unroll
  for (int f = 0; f < 8; ++f){ acc[f][0] = zero; acc[f][1] = zero; }
  float den[2] = {0.f, 0.f};
  short* Pw = &Pl[wave][0];

  int cur = 0;
  for (int st = 0; st < ns; ++st){
    const int j0 = kvlo + st * 64;
    if (st + 1 < ns){
      ATTN_STAGE(cur ^ 1, j0 + 64)
      asm volatile("s_waitcnt vmcnt(8)" ::: "memory");
    } else {
      asm volatile("s_waitcnt vmcnt(0)" ::: "memory");
    }
    __builtin_amdgcn_s_barrier();
    asm volatile("" ::: "memory");

    // ---- swapped QK^T: sc[kvs][qs], lane = S[kv=j0+kvs*16+hg*4+r][q=..+lr] ----
    f32x4 sc[4][2];
    __builtin_amdgcn_s_setprio(1);
    #pragma unroll
    for (int kvs = 0; kvs < 4; ++kvs){
      sc[kvs][0] = zero; sc[kvs][1] = zero;
      #pragma unroll
      for (int sl = 0; sl < 4; ++sl){
        bf16x8 kf = *(const bf16x8*)&Kl[cur][(kvs * 4 + sl) * 512 + lane * 8];
        sc[kvs][0] = mfma16(kf, qf[0][sl], sc[kvs][0]);
        sc[kvs][1] = mfma16(kf, qf[1][sl], sc[kvs][1]);
      }
    }
    __builtin_amdgcn_s_setprio(0);

    // ---- causal mask per q-set ----
    if (j0 + 63 > qt0 + wave * 32){
      #pragma unroll
      for (int qs = 0; qs < 2; ++qs){
        int qr0 = qt0 + wave * 32 + qs * 16;
        #pragma unroll
        for (int kvs = 0; kvs < 4; ++kvs){
          int kv0 = j0 + kvs * 16 + hg * 4;
          #pragma unroll
          for (int r = 0; r < 4; ++r)
            if (kv0 + r > qr0 + lr) sc[kvs][qs][r] = -INFINITY;
        }
      }
    }

    // ---- V prefetch for both kv-halves (pipelines on DS queue) ----
    bf16x8 vfa[8], vfb[8];
    #pragma unroll
    for (int f = 0; f < 8; ++f){
      vfa[f] = *(const bf16x8*)&Vl[cur][f * 512 + lane * 8];
      vfb[f] = *(const bf16x8*)&Vl[cur][(8 + f) * 512 + lane * 8];
    }

    // ---- per q-set: exp2 + cvt_pk + P roundtrip + PV (P buffer reused;
    //      same-wave DS ops are ordered, so no barrier needed) ----
    #pragma unroll
    for (int qs = 0; qs < 2; ++qs){
      float p[4][4];
      #pragma unroll
      for (int kvs = 0; kvs < 4; ++kvs){
        #pragma unroll
        for (int r = 0; r < 4; ++r){
          p[kvs][r] = __builtin_exp2f(sc[kvs][qs][r]);
          den[qs] += p[kvs][r];
        }
      }
      #pragma unroll
      for (int kvs = 0; kvs < 4; ++kvs){
        u32x2 w = { cvtpk(p[kvs][0], p[kvs][1]), cvtpk(p[kvs][2], p[kvs][3]) };
        *(u32x2*)(&Pw[lr * PPS + kvs * 16 + hg * 4]) = w;
      }
      bf16x8 pf0 = *(const bf16x8*)(&Pw[lr * PPS + hg * 8]);
      bf16x8 pf1 = *(const bf16x8*)(&Pw[lr * PPS + 32 + hg * 8]);

      __builtin_amdgcn_s_setprio(1);
      #pragma unroll
      for (int f = 0; f < 8; ++f){
        acc[f][qs] = mfma16(vfa[f], pf0, acc[f][qs]);
        acc[f][qs] = mfma16(vfb[f], pf1, acc[f][qs]);
      }
      __builtin_amdgcn_s_setprio(0);
    }

    asm volatile("" ::: "memory");
    __builtin_amdgcn_s_barrier();
    cur ^= 1;
  }

  // ---- den: one-time cross-lane reduce ----
  #pragma unroll
  for (int qs = 0; qs < 2; ++qs){
    den[qs] += __shfl_xor(den[qs], 16);
    den[qs] += __shfl_xor(den[qs], 32);
  }

  // ---- write UNNORMALIZED partials (bf16) + den (f32); item = 128 rows ----
  const int pidx = b * 144 + i;
  short* Op = Opart + (size_t)pidx * 16384;
  #pragma unroll
  for (int qs = 0; qs < 2; ++qs){
    const int rowblk = wave * 2 + qs;      // 0..7
    #pragma unroll
    for (int f = 0; f < 8; ++f){
      s16x4 ov;
      #pragma unroll
      for (int r = 0; r < 4; ++r) ov[r] = f2bf(acc[f][qs][r]);
      *(s16x4*)(Op + (rowblk * 16 + lr) * 128 + f * 16 + hg * 4) = ov;
    }
    if (hg == 0)
      Dn[pidx * 128 + rowblk * 16 + lr] = den[qs];
  }
}

// ---------------------------------------------------------------------------
// Kernel 3: combine — plain sum of unnormalized partials (r15/r18 verified).
// ---------------------------------------------------------------------------
__global__ __launch_bounds__(512) void combine(const short* __restrict__ Opart,
    const float* __restrict__ Dn, float* __restrict__ out){
  const int bx = blockIdx.x, b = blockIdx.y;
  const int t = bx >> 1, sub = bx & 1;
  const int row = threadIdx.x >> 3;
  const int cgp = threadIdx.x & 7;
  const int rI = sub * 64 + row;           // 0..127 within tile
  const int a = t >> 2, bb = t & 3;
  const int Ffull = a * (2 * a + bb - 1);
  const int nfull = a + (bb == 3);
  const int nc = a + 1;
  const int ipart = (bb == 2) ? 120 + a : (bb == 1) ? 128 + a : 136 + a;

  float L = 0.f;
  float o[16];
  #pragma unroll
  for (int e = 0; e < 16; ++e) o[e] = 0.f;
  for (int cc = 0; cc < nc; ++cc){
    int ii = (cc < nfull) ? Ffull + cc : ipart;
    int id = b * 144 + ii;
    L += Dn[id * 128 + rI];
    const short* op = Opart + (size_t)id * 16384 + rI * 128 + cgp * 16;
    bf16x8 v0 = *(const bf16x8*)(op);
    bf16x8 v1 = *(const bf16x8*)(op + 8);
    #pragma unroll
    for (int e = 0; e < 8; ++e){
      o[e]     += bf2f(v0[e]);
      o[8 + e] += bf2f(v1[e]);
    }
  }
  float inv = 1.f / L;
  float* dst = out + ((size_t)b * S_LEN + t * 128 + rI) * HEAD + cgp * 16;
  #pragma unroll
  for (int e4 = 0; e4 < 4; ++e4){
    float4 w4 = { o[e4*4]*inv, o[e4*4+1]*inv, o[e4*4+2]*inv, o[e4*4+3]*inv };
    *(float4*)(dst + e4 * 4) = w4;
  }
}

// ---------------------------------------------------------------------------
extern "C" void kernel_launch(void* const* d_in, const int* in_sizes, int n_in,
                              void* d_out, int out_size, void* d_ws, size_t ws_size,
                              hipStream_t stream){
  const float* x  = (const float*)d_in[0];
  const float* Wq = (const float*)d_in[1];
  const float* bq = (const float*)d_in[2];
  const float* Wk = (const float*)d_in[3];
  const float* bk = (const float*)d_in[4];
  const float* Wv = (const float*)d_in[5];
  const float* bv = (const float*)d_in[6];
  float* out = (float*)d_out;

  char* ws = (char*)d_ws;
  short* WT    = (short*)(ws);                         // 768 KB
  float* bias  = (float*)(ws + 786432);                // 1.5 KB
  short* Qb    = (short*)(ws + (1u << 20));            // 4 MB
  short* Kb    = (short*)(ws + (1u << 20) + 4194304u); // 4 MB
  short* VTb   = (short*)(ws + (1u << 20) + 8388608u); // 4 MB
  short* Opart = (short*)(ws + 13631488u);             // 576*32KB = 18.9 MB
  float* Dn    = (float*)(ws + 32505856u);             // 288 KB

  prep_w<<<1536, 256, 0, stream>>>(Wq, bq, Wk, bk, Wv, bv, WT, bias);
  qkv_proj<<<256, 1024, 0, stream>>>(x, WT, bias, Qb, Kb, VTb);
  attn<<<dim3(4, 144), 256, 0, stream>>>(Qb, Kb, VTb, Opart, Dn);
  combine<<<dim3(64, 4), 512, 0, stream>>>(Opart, Dn, out);
}

// Round 20
// 89.832 us; speedup vs baseline: 1.1837x; 1.1837x over previous
//
#include <hip/hip_runtime.h>
#include <hip/hip_bf16.h>
#include <math.h>

#define S_LEN 4096
#define EMB   1024
#define HEAD  128

typedef short bf16x8 __attribute__((ext_vector_type(8)));
typedef short s16x4  __attribute__((ext_vector_type(4)));
typedef float f32x4  __attribute__((ext_vector_type(4)));
typedef unsigned u32x2 __attribute__((ext_vector_type(2)));
typedef unsigned u32x4 __attribute__((ext_vector_type(4)));

static __device__ __forceinline__ short f2bf(float x){
  unsigned u = __builtin_bit_cast(unsigned, x);
  u += 0x7fffu + ((u >> 16) & 1u);
  return (short)(u >> 16);
}
static __device__ __forceinline__ float bf2f(short s){
  unsigned u = ((unsigned)(unsigned short)s) << 16;
  return __builtin_bit_cast(float, u);
}
// packed f32x2 -> bf16x2 (gfx950 v_cvt_pk_bf16_f32): D.lo = bf16(a), D.hi = bf16(b)
static __device__ __forceinline__ unsigned cvtpk(float a, float b){
  unsigned r;
  asm("v_cvt_pk_bf16_f32 %0, %1, %2" : "=v"(r) : "v"(a), "v"(b));
  return r;
}
static __device__ __forceinline__ f32x4 mfma16(bf16x8 a, bf16x8 b, f32x4 c){
  return __builtin_amdgcn_mfma_f32_16x16x32_bf16(a, b, c, 0, 0, 0);
}
static __device__ __forceinline__ void gload16(const void* g, void* l){
  __builtin_amdgcn_global_load_lds((const __attribute__((address_space(1))) unsigned*)g,
                                   (__attribute__((address_space(3))) unsigned*)l, 16, 0, 0);
}

// ---------------------------------------------------------------------------
// Kernel 0: WT_cat[384][1024] bf16 (transposed). Q cols pre-scaled by
// 1/sqrt(128)*log2(e) so attn uses exp2 (round-14 verified).
// ---------------------------------------------------------------------------
__global__ void prep_w(const float* __restrict__ Wq, const float* __restrict__ bq,
                       const float* __restrict__ Wk, const float* __restrict__ bk,
                       const float* __restrict__ Wv, const float* __restrict__ bv,
                       short* __restrict__ WT, float* __restrict__ bias){
  const float QS = 0.08838834764831845f * 1.4426950408889634f;
  int idx = blockIdx.x * 256 + threadIdx.x;
  int nc  = idx >> 10;
  int k   = idx & 1023;
  int mat = nc >> 7;
  int n   = nc & 127;
  const float* W = (mat == 0) ? Wq : (mat == 1) ? Wk : Wv;
  float s = (mat == 0) ? QS : 1.0f;
  WT[idx] = f2bf(W[k * HEAD + n] * s);
  if (idx < 384){
    int m2 = idx >> 7, n2 = idx & 127;
    const float* bsrc = (m2 == 0) ? bq : (m2 == 1) ? bk : bv;
    float s2 = (m2 == 0) ? QS : 1.0f;
    bias[idx] = bsrc[n2] * s2;
  }
}

// ---------------------------------------------------------------------------
// Kernel 1: fused QKV projection, 1024 threads, cvt_pk A-frags (r18 verified).
// ---------------------------------------------------------------------------
__global__ __launch_bounds__(1024) void qkv_proj(const float* __restrict__ x,
    const short* __restrict__ WT, const float* __restrict__ bias,
    short* __restrict__ Qo, short* __restrict__ Ko, short* __restrict__ VTo){
  __shared__ __align__(16) short Sm[2][32768];   // per buf: W 24576sh + X 8192sh

  const int tid = threadIdx.x;
  const int wave = tid >> 6, lane = tid & 63, lr = lane & 15, hg = lane >> 4;
  const int wrg = wave >> 3, cg = wave & 7, fbase = cg * 3;
  const int row0 = blockIdx.x * 64;

  const f32x4 zero = {0.f, 0.f, 0.f, 0.f};
  f32x4 acc[2][3];
  #pragma unroll
  for (int rf = 0; rf < 2; ++rf)
    #pragma unroll
    for (int f = 0; f < 3; ++f) acc[rf][f] = zero;

#define WL(buf) (&Sm[buf][0])
#define XL(buf) ((float*)&Sm[buf][24576])

#define QKV_STAGE(buf, k0)                                                         \
  {                                                                                \
    _Pragma("unroll")                                                              \
    for (int s = 0; s < 3; ++s){                                                   \
      int slot = s * 16 + wave;                                                    \
      int ff = slot >> 1, ks = slot & 1;                                           \
      gload16(WT + (size_t)(ff * 16 + lr) * 1024 + (k0) + ks * 32 + hg * 8,        \
              WL(buf) + slot * 512);                                               \
    }                                                                              \
    {                                                                              \
      int rr = wave * 4 + hg;                                                      \
      int cs = lr ^ (rr & 15);                                                     \
      gload16(x + (size_t)(row0 + rr) * 1024 + (k0) + cs * 4,                      \
              XL(buf) + wave * 256);                                               \
    }                                                                              \
  }

  QKV_STAGE(0, 0)

  int cur = 0;
  for (int t = 0; t < 16; ++t){
    if (t < 15){
      QKV_STAGE(cur ^ 1, (t + 1) * 64)
      asm volatile("s_waitcnt vmcnt(4)" ::: "memory");
    } else {
      asm volatile("s_waitcnt vmcnt(0)" ::: "memory");
    }
    __builtin_amdgcn_s_barrier();
    asm volatile("" ::: "memory");

    bf16x8 a[2][2];
    #pragma unroll
    for (int rf = 0; rf < 2; ++rf){
      const int xr = wrg * 32 + rf * 16 + lr;
      #pragma unroll
      for (int ks = 0; ks < 2; ++ks){
        int s0 = ks * 8 + hg * 2;
        f32x4 xa = *(const f32x4*)&XL(cur)[xr * 64 + ((s0 ^ lr) << 2)];
        f32x4 xb = *(const f32x4*)&XL(cur)[xr * 64 + (((s0 + 1) ^ lr) << 2)];
        u32x4 pk = { cvtpk(xa[0], xa[1]), cvtpk(xa[2], xa[3]),
                     cvtpk(xb[0], xb[1]), cvtpk(xb[2], xb[3]) };
        a[rf][ks] = __builtin_bit_cast(bf16x8, pk);
      }
    }
    __builtin_amdgcn_s_setprio(1);
    #pragma unroll
    for (int fi = 0; fi < 3; ++fi){
      #pragma unroll
      for (int ks = 0; ks < 2; ++ks){
        bf16x8 bfr = *(const bf16x8*)&WL(cur)[((fbase + fi) * 2 + ks) * 512 + lane * 8];
        acc[0][fi] = mfma16(a[0][ks], bfr, acc[0][fi]);
        acc[1][fi] = mfma16(a[1][ks], bfr, acc[1][fi]);
      }
    }
    __builtin_amdgcn_s_setprio(0);
    asm volatile("" ::: "memory");
    __builtin_amdgcn_s_barrier();
    cur ^= 1;
  }

  short* Vb = &Sm[0][0];   // 128 x 72 pitch bounce (aliases W buf, loop done)
  #pragma unroll
  for (int rf = 0; rf < 2; ++rf){
    #pragma unroll
    for (int fi = 0; fi < 3; ++fi){
      int f = fbase + fi;
      float bb = bias[f * 16 + lr];
      int rloc = wrg * 32 + rf * 16 + hg * 4;
      u32x2 pk = { cvtpk(acc[rf][fi][0] + bb, acc[rf][fi][1] + bb),
                   cvtpk(acc[rf][fi][2] + bb, acc[rf][fi][3] + bb) };
      s16x4 ov = __builtin_bit_cast(s16x4, pk);
      if (f < 16){
        short* dst = (f < 8) ? Qo : Ko;
        int col = (f & 7) * 16 + lr;
        #pragma unroll
        for (int r = 0; r < 4; ++r)
          dst[(size_t)(row0 + rloc + r) * HEAD + col] = ov[r];
      } else {
        int vcol = (f - 16) * 16 + lr;
        #pragma unroll
        for (int r = 0; r < 4; ++r)
          Vb[vcol * 72 + rloc + r] = ov[r];
      }
    }
  }
  __syncthreads();
  {
    int vcol = tid >> 3, sq = tid & 7;
    bf16x8 v = *(const bf16x8*)&Vb[vcol * 72 + sq * 8];
    int bb2 = row0 >> 12, ss = row0 & 4095;
    *(bf16x8*)(VTo + ((size_t)(bb2 * HEAD + vcol)) * S_LEN + ss + sq * 8) = v;
  }
}

// ---------------------------------------------------------------------------
// Kernel 2: split-KV causal flash — r15/r18 structure VERBATIM (best measured:
// 4 waves x 32 q-rows, chunk 512, step 32, dbuf + 2 barriers, fixed-max
// exp2 softmax, cvt_pk P-pack, batched P roundtrip). Epilogue pack via cvt_pk.
// ---------------------------------------------------------------------------
#define PPS 36

__global__ __launch_bounds__(256) void attn(const short* __restrict__ Q,
    const short* __restrict__ K, const short* __restrict__ VT,
    short* __restrict__ Opart, float* __restrict__ Dn){
  __shared__ __align__(16) short Kl[2][4096];
  __shared__ __align__(16) short Vl[2][4096];
  __shared__ __align__(16) short Pl[4][2][16 * PPS];

  const int tid = threadIdx.x;
  const int wave = tid >> 6, lane = tid & 63, lr = lane & 15, hg = lane >> 4;
  const int b = blockIdx.x;
  const int i = blockIdx.y;     // 0..143, heavy-first

  int t, c, ns;
  if (i < 120){
    int acc2 = 0; t = 0; c = 0;
    #pragma unroll
    for (int tt = 0; tt < 32; ++tt){
      int nf = (tt >> 2) + ((tt & 3) == 3);
      if (i >= acc2 && i < acc2 + nf){ t = tt; c = i - acc2; }
      acc2 += nf;
    }
    ns = 16;
  } else if (i < 128){ int k = i - 120; t = 4 * k + 2; c = k; ns = 12; }
  else if (i < 136)  { int k = i - 128; t = 4 * k + 1; c = k; ns = 8; }
  else               { int k = i - 136; t = 4 * k;     c = k; ns = 4; }

  const int qt0  = t * 128;
  const int kvlo = c << 9;

  const short* Qg = Q  + ((size_t)b * S_LEN + qt0 + wave * 32) * HEAD;
  const short* Kg = K  + (size_t)b * S_LEN * HEAD;
  const short* Vg = VT + (size_t)b * HEAD * S_LEN;

  bf16x8 qf[2][4];
  #pragma unroll
  for (int qs = 0; qs < 2; ++qs)
    #pragma unroll
    for (int sl = 0; sl < 4; ++sl)
      qf[qs][sl] = *(const bf16x8*)(Qg + (size_t)(qs * 16 + lr) * HEAD + sl * 32 + hg * 8);

  // wave w stages K slots {2w,2w+1} and V slots {2w,2w+1} (r8/r15 addrs)
#define ATTN_STAGE(buf, j0)                                                        \
  {                                                                                \
    _Pragma("unroll")                                                              \
    for (int q = 0; q < 2; ++q){                                                   \
      int s = wave * 2 + q;                                                        \
      gload16(Kg + (size_t)((j0) + (s >> 2) * 16 + lr) * HEAD + (s & 3) * 32 + hg * 8, \
              &Kl[buf][s * 512]);                                                  \
    }                                                                              \
    _Pragma("unroll")                                                              \
    for (int q = 0; q < 2; ++q){                                                   \
      int s = wave * 2 + q;                                                        \
      gload16(Vg + (size_t)(s * 16 + lr) * S_LEN + (j0) + hg * 8,                  \
              &Vl[buf][s * 512]);                                                  \
    }                                                                              \
  }

  ATTN_STAGE(0, kvlo)

  const f32x4 zero = {0.f, 0.f, 0.f, 0.f};
  f32x4 acc[8][2];
  #pragma unroll
  for (int f = 0; f < 8; ++f){ acc[f][0] = zero; acc[f][1] = zero; }
  float den[2] = {0.f, 0.f};

  int cur = 0;
  for (int st = 0; st < ns; ++st){
    const int j0 = kvlo + st * 32;
    if (st + 1 < ns){
      ATTN_STAGE(cur ^ 1, j0 + 32)
      asm volatile("s_waitcnt vmcnt(4)" ::: "memory");
    } else {
      asm volatile("s_waitcnt vmcnt(0)" ::: "memory");
    }
    __builtin_amdgcn_s_barrier();
    asm volatile("" ::: "memory");

    // ---- swapped QK^T: sc[kvs][qs], lane = S[kv=j0+kvs*16+hg*4+r][q=..+lr] ----
    f32x4 sc[2][2];
    __builtin_amdgcn_s_setprio(1);
    #pragma unroll
    for (int kvs = 0; kvs < 2; ++kvs){
      sc[kvs][0] = zero; sc[kvs][1] = zero;
      #pragma unroll
      for (int sl = 0; sl < 4; ++sl){
        bf16x8 kf = *(const bf16x8*)&Kl[cur][(kvs * 4 + sl) * 512 + lane * 8];
        sc[kvs][0] = mfma16(kf, qf[0][sl], sc[kvs][0]);
        sc[kvs][1] = mfma16(kf, qf[1][sl], sc[kvs][1]);
      }
    }
    __builtin_amdgcn_s_setprio(0);

    // ---- causal mask per q-set ----
    if (j0 + 31 > qt0 + wave * 32){
      #pragma unroll
      for (int qs = 0; qs < 2; ++qs){
        int qr0 = qt0 + wave * 32 + qs * 16;
        #pragma unroll
        for (int kvs = 0; kvs < 2; ++kvs){
          int kv0 = j0 + kvs * 16 + hg * 4;
          #pragma unroll
          for (int r = 0; r < 4; ++r)
            if (kv0 + r > qr0 + lr) sc[kvs][qs][r] = -INFINITY;
        }
      }
    }

    // ---- fixed-max softmax: exp2 + packed cvt_pk bf16 ----
    s16x4 pb[2][2];
    #pragma unroll
    for (int qs = 0; qs < 2; ++qs){
      float p0[4], p1[4];
      #pragma unroll
      for (int r = 0; r < 4; ++r){
        p0[r] = __builtin_exp2f(sc[0][qs][r]);
        p1[r] = __builtin_exp2f(sc[1][qs][r]);
        den[qs] += p0[r] + p1[r];
      }
      u32x2 w0 = { cvtpk(p0[0], p0[1]), cvtpk(p0[2], p0[3]) };
      u32x2 w1 = { cvtpk(p1[0], p1[1]), cvtpk(p1[2], p1[3]) };
      pb[qs][0] = __builtin_bit_cast(s16x4, w0);
      pb[qs][1] = __builtin_bit_cast(s16x4, w1);
    }

    // ---- all P writes, then V prefetch, then pf reads (r14 batched) ----
    #pragma unroll
    for (int qs = 0; qs < 2; ++qs){
      short* Pw = &Pl[wave][qs][0];
      *(s16x4*)(&Pw[lr * PPS + hg * 4])      = pb[qs][0];
      *(s16x4*)(&Pw[lr * PPS + 16 + hg * 4]) = pb[qs][1];
    }
    bf16x8 vf[8];
    #pragma unroll
    for (int f = 0; f < 8; ++f)
      vf[f] = *(const bf16x8*)&Vl[cur][f * 512 + lane * 8];
    bf16x8 pf[2];
    #pragma unroll
    for (int qs = 0; qs < 2; ++qs)
      pf[qs] = *(const bf16x8*)(&Pl[wave][qs][lr * PPS + hg * 8]);

    // ---- swapped PV ----
    __builtin_amdgcn_s_setprio(1);
    #pragma unroll
    for (int f = 0; f < 8; ++f){
      acc[f][0] = mfma16(vf[f], pf[0], acc[f][0]);
      acc[f][1] = mfma16(vf[f], pf[1], acc[f][1]);
    }
    __builtin_amdgcn_s_setprio(0);

    asm volatile("" ::: "memory");
    __builtin_amdgcn_s_barrier();
    cur ^= 1;
  }

  // ---- den: one-time cross-lane reduce ----
  #pragma unroll
  for (int qs = 0; qs < 2; ++qs){
    den[qs] += __shfl_xor(den[qs], 16);
    den[qs] += __shfl_xor(den[qs], 32);
  }

  // ---- write UNNORMALIZED partials (bf16) + den (f32); item = 128 rows ----
  const int pidx = b * 144 + i;
  short* Op = Opart + (size_t)pidx * 16384;
  #pragma unroll
  for (int qs = 0; qs < 2; ++qs){
    const int rowblk = wave * 2 + qs;      // 0..7
    #pragma unroll
    for (int f = 0; f < 8; ++f){
      u32x2 pk = { cvtpk(acc[f][qs][0], acc[f][qs][1]),
                   cvtpk(acc[f][qs][2], acc[f][qs][3]) };
      *(u32x2*)(Op + (rowblk * 16 + lr) * 128 + f * 16 + hg * 4) = pk;
    }
    if (hg == 0)
      Dn[pidx * 128 + rowblk * 16 + lr] = den[qs];
  }
}

// ---------------------------------------------------------------------------
// Kernel 3: combine — plain sum of unnormalized partials (r15/r18 verified).
// ---------------------------------------------------------------------------
__global__ __launch_bounds__(512) void combine(const short* __restrict__ Opart,
    const float* __restrict__ Dn, float* __restrict__ out){
  const int bx = blockIdx.x, b = blockIdx.y;
  const int t = bx >> 1, sub = bx & 1;
  const int row = threadIdx.x >> 3;
  const int cgp = threadIdx.x & 7;
  const int rI = sub * 64 + row;           // 0..127 within tile
  const int a = t >> 2, bb = t & 3;
  const int Ffull = a * (2 * a + bb - 1);
  const int nfull = a + (bb == 3);
  const int nc = a + 1;
  const int ipart = (bb == 2) ? 120 + a : (bb == 1) ? 128 + a : 136 + a;

  float L = 0.f;
  float o[16];
  #pragma unroll
  for (int e = 0; e < 16; ++e) o[e] = 0.f;
  for (int cc = 0; cc < nc; ++cc){
    int ii = (cc < nfull) ? Ffull + cc : ipart;
    int id = b * 144 + ii;
    L += Dn[id * 128 + rI];
    const short* op = Opart + (size_t)id * 16384 + rI * 128 + cgp * 16;
    bf16x8 v0 = *(const bf16x8*)(op);
    bf16x8 v1 = *(const bf16x8*)(op + 8);
    #pragma unroll
    for (int e = 0; e < 8; ++e){
      o[e]     += bf2f(v0[e]);
      o[8 + e] += bf2f(v1[e]);
    }
  }
  float inv = 1.f / L;
  float* dst = out + ((size_t)b * S_LEN + t * 128 + rI) * HEAD + cgp * 16;
  #pragma unroll
  for (int e4 = 0; e4 < 4; ++e4){
    float4 w4 = { o[e4*4]*inv, o[e4*4+1]*inv, o[e4*4+2]*inv, o[e4*4+3]*inv };
    *(float4*)(dst + e4 * 4) = w4;
  }
}

// ---------------------------------------------------------------------------
extern "C" void kernel_launch(void* const* d_in, const int* in_sizes, int n_in,
                              void* d_out, int out_size, void* d_ws, size_t ws_size,
                              hipStream_t stream){
  const float* x  = (const float*)d_in[0];
  const float* Wq = (const float*)d_in[1];
  const float* bq = (const float*)d_in[2];
  const float* Wk = (const float*)d_in[3];
  const float* bk = (const float*)d_in[4];
  const float* Wv = (const float*)d_in[5];
  const float* bv = (const float*)d_in[6];
  float* out = (float*)d_out;

  char* ws = (char*)d_ws;
  short* WT    = (short*)(ws);                         // 768 KB
  float* bias  = (float*)(ws + 786432);                // 1.5 KB
  short* Qb    = (short*)(ws + (1u << 20));            // 4 MB
  short* Kb    = (short*)(ws + (1u << 20) + 4194304u); // 4 MB
  short* VTb   = (short*)(ws + (1u << 20) + 8388608u); // 4 MB
  short* Opart = (short*)(ws + 13631488u);             // 576*32KB = 18.9 MB
  float* Dn    = (float*)(ws + 32505856u);             // 288 KB

  prep_w<<<1536, 256, 0, stream>>>(Wq, bq, Wk, bk, Wv, bv, WT, bias);
  qkv_proj<<<256, 1024, 0, stream>>>(x, WT, bias, Qb, Kb, VTb);
  attn<<<dim3(4, 144), 256, 0, stream>>>(Qb, Kb, VTb, Opart, Dn);
  combine<<<dim3(64, 4), 512, 0, stream>>>(Opart, Dn, out);
}

// Round 21
// 89.692 us; speedup vs baseline: 1.1855x; 1.0016x over previous
//
#include <hip/hip_runtime.h>
#include <hip/hip_bf16.h>
#include <math.h>

#define S_LEN 4096
#define EMB   1024
#define HEAD  128

typedef short bf16x8 __attribute__((ext_vector_type(8)));
typedef short s16x4  __attribute__((ext_vector_type(4)));
typedef float f32x4  __attribute__((ext_vector_type(4)));
typedef unsigned u32x2 __attribute__((ext_vector_type(2)));
typedef unsigned u32x4 __attribute__((ext_vector_type(4)));

static __device__ __forceinline__ short f2bf(float x){
  unsigned u = __builtin_bit_cast(unsigned, x);
  u += 0x7fffu + ((u >> 16) & 1u);
  return (short)(u >> 16);
}
static __device__ __forceinline__ float bf2f(short s){
  unsigned u = ((unsigned)(unsigned short)s) << 16;
  return __builtin_bit_cast(float, u);
}
// packed f32x2 -> bf16x2 (gfx950 v_cvt_pk_bf16_f32): D.lo = bf16(a), D.hi = bf16(b)
static __device__ __forceinline__ unsigned cvtpk(float a, float b){
  unsigned r;
  asm("v_cvt_pk_bf16_f32 %0, %1, %2" : "=v"(r) : "v"(a), "v"(b));
  return r;
}
static __device__ __forceinline__ f32x4 mfma16(bf16x8 a, bf16x8 b, f32x4 c){
  return __builtin_amdgcn_mfma_f32_16x16x32_bf16(a, b, c, 0, 0, 0);
}
static __device__ __forceinline__ void gload16(const void* g, void* l){
  __builtin_amdgcn_global_load_lds((const __attribute__((address_space(1))) unsigned*)g,
                                   (__attribute__((address_space(3))) unsigned*)l, 16, 0, 0);
}

// ---------------------------------------------------------------------------
// Kernel 0: WT_cat[384][1024] bf16 (transposed). Q cols pre-scaled by
// 1/sqrt(128)*log2(e) so attn uses exp2 (round-14 verified).
// ---------------------------------------------------------------------------
__global__ void prep_w(const float* __restrict__ Wq, const float* __restrict__ bq,
                       const float* __restrict__ Wk, const float* __restrict__ bk,
                       const float* __restrict__ Wv, const float* __restrict__ bv,
                       short* __restrict__ WT, float* __restrict__ bias){
  const float QS = 0.08838834764831845f * 1.4426950408889634f;
  int idx = blockIdx.x * 256 + threadIdx.x;
  int nc  = idx >> 10;
  int k   = idx & 1023;
  int mat = nc >> 7;
  int n   = nc & 127;
  const float* W = (mat == 0) ? Wq : (mat == 1) ? Wk : Wv;
  float s = (mat == 0) ? QS : 1.0f;
  WT[idx] = f2bf(W[k * HEAD + n] * s);
  if (idx < 384){
    int m2 = idx >> 7, n2 = idx & 127;
    const float* bsrc = (m2 == 0) ? bq : (m2 == 1) ? bk : bv;
    float s2 = (m2 == 0) ? QS : 1.0f;
    bias[idx] = bsrc[n2] * s2;
  }
}

// ---------------------------------------------------------------------------
// Kernel 1: fused QKV projection, 1024 threads, cvt_pk A-frags (r18/r20).
// ---------------------------------------------------------------------------
__global__ __launch_bounds__(1024) void qkv_proj(const float* __restrict__ x,
    const short* __restrict__ WT, const float* __restrict__ bias,
    short* __restrict__ Qo, short* __restrict__ Ko, short* __restrict__ VTo){
  __shared__ __align__(16) short Sm[2][32768];   // per buf: W 24576sh + X 8192sh

  const int tid = threadIdx.x;
  const int wave = tid >> 6, lane = tid & 63, lr = lane & 15, hg = lane >> 4;
  const int wrg = wave >> 3, cg = wave & 7, fbase = cg * 3;
  const int row0 = blockIdx.x * 64;

  const f32x4 zero = {0.f, 0.f, 0.f, 0.f};
  f32x4 acc[2][3];
  #pragma unroll
  for (int rf = 0; rf < 2; ++rf)
    #pragma unroll
    for (int f = 0; f < 3; ++f) acc[rf][f] = zero;

#define WL(buf) (&Sm[buf][0])
#define XL(buf) ((float*)&Sm[buf][24576])

#define QKV_STAGE(buf, k0)                                                         \
  {                                                                                \
    _Pragma("unroll")                                                              \
    for (int s = 0; s < 3; ++s){                                                   \
      int slot = s * 16 + wave;                                                    \
      int ff = slot >> 1, ks = slot & 1;                                           \
      gload16(WT + (size_t)(ff * 16 + lr) * 1024 + (k0) + ks * 32 + hg * 8,        \
              WL(buf) + slot * 512);                                               \
    }                                                                              \
    {                                                                              \
      int rr = wave * 4 + hg;                                                      \
      int cs = lr ^ (rr & 15);                                                     \
      gload16(x + (size_t)(row0 + rr) * 1024 + (k0) + cs * 4,                      \
              XL(buf) + wave * 256);                                               \
    }                                                                              \
  }

  QKV_STAGE(0, 0)

  int cur = 0;
  for (int t = 0; t < 16; ++t){
    if (t < 15){
      QKV_STAGE(cur ^ 1, (t + 1) * 64)
      asm volatile("s_waitcnt vmcnt(4)" ::: "memory");
    } else {
      asm volatile("s_waitcnt vmcnt(0)" ::: "memory");
    }
    __builtin_amdgcn_s_barrier();
    asm volatile("" ::: "memory");

    bf16x8 a[2][2];
    #pragma unroll
    for (int rf = 0; rf < 2; ++rf){
      const int xr = wrg * 32 + rf * 16 + lr;
      #pragma unroll
      for (int ks = 0; ks < 2; ++ks){
        int s0 = ks * 8 + hg * 2;
        f32x4 xa = *(const f32x4*)&XL(cur)[xr * 64 + ((s0 ^ lr) << 2)];
        f32x4 xb = *(const f32x4*)&XL(cur)[xr * 64 + (((s0 + 1) ^ lr) << 2)];
        u32x4 pk = { cvtpk(xa[0], xa[1]), cvtpk(xa[2], xa[3]),
                     cvtpk(xb[0], xb[1]), cvtpk(xb[2], xb[3]) };
        a[rf][ks] = __builtin_bit_cast(bf16x8, pk);
      }
    }
    __builtin_amdgcn_s_setprio(1);
    #pragma unroll
    for (int fi = 0; fi < 3; ++fi){
      #pragma unroll
      for (int ks = 0; ks < 2; ++ks){
        bf16x8 bfr = *(const bf16x8*)&WL(cur)[((fbase + fi) * 2 + ks) * 512 + lane * 8];
        acc[0][fi] = mfma16(a[0][ks], bfr, acc[0][fi]);
        acc[1][fi] = mfma16(a[1][ks], bfr, acc[1][fi]);
      }
    }
    __builtin_amdgcn_s_setprio(0);
    asm volatile("" ::: "memory");
    __builtin_amdgcn_s_barrier();
    cur ^= 1;
  }

  short* Vb = &Sm[0][0];   // 128 x 72 pitch bounce (aliases W buf, loop done)
  #pragma unroll
  for (int rf = 0; rf < 2; ++rf){
    #pragma unroll
    for (int fi = 0; fi < 3; ++fi){
      int f = fbase + fi;
      float bb = bias[f * 16 + lr];
      int rloc = wrg * 32 + rf * 16 + hg * 4;
      u32x2 pk = { cvtpk(acc[rf][fi][0] + bb, acc[rf][fi][1] + bb),
                   cvtpk(acc[rf][fi][2] + bb, acc[rf][fi][3] + bb) };
      s16x4 ov = __builtin_bit_cast(s16x4, pk);
      if (f < 16){
        short* dst = (f < 8) ? Qo : Ko;
        int col = (f & 7) * 16 + lr;
        #pragma unroll
        for (int r = 0; r < 4; ++r)
          dst[(size_t)(row0 + rloc + r) * HEAD + col] = ov[r];
      } else {
        int vcol = (f - 16) * 16 + lr;
        #pragma unroll
        for (int r = 0; r < 4; ++r)
          Vb[vcol * 72 + rloc + r] = ov[r];
      }
    }
  }
  __syncthreads();
  {
    int vcol = tid >> 3, sq = tid & 7;
    bf16x8 v = *(const bf16x8*)&Vb[vcol * 72 + sq * 8];
    int bb2 = row0 >> 12, ss = row0 & 4095;
    *(bf16x8*)(VTo + ((size_t)(bb2 * HEAD + vcol)) * S_LEN + ss + sq * 8) = v;
  }
}

// ---------------------------------------------------------------------------
// Kernel 2: split-KV causal flash, r20 base + T15 DEFERRED PV:
// step st computes QK^T(st) and PV(st-1) concurrently (PV uses carried pfp
// registers + triple-buffered V read from Vl[(st-1)%3]); softmax(st)'s
// P-roundtrip then has a full barrier-to-barrier to land. Write-safety:
// stage(st+1)->V[(st+1)%3] != V[(st-1)%3]; V[(st-1)%3] overwritten only by
// stage(st+2), issued after this step's end barrier. Only pfp (8 VGPR)
// crosses the barrier. K dbuf 16KB + V tribuf 24KB + P 9KB = 49KB LDS.
// ---------------------------------------------------------------------------
#define PPS 36

__global__ __launch_bounds__(256) void attn(const short* __restrict__ Q,
    const short* __restrict__ K, const short* __restrict__ VT,
    short* __restrict__ Opart, float* __restrict__ Dn){
  __shared__ __align__(16) short Kl[2][4096];
  __shared__ __align__(16) short Vl[3][4096];
  __shared__ __align__(16) short Pl[4][2][16 * PPS];

  const int tid = threadIdx.x;
  const int wave = tid >> 6, lane = tid & 63, lr = lane & 15, hg = lane >> 4;
  const int b = blockIdx.x;
  const int i = blockIdx.y;     // 0..143, heavy-first

  int t, c, ns;
  if (i < 120){
    int acc2 = 0; t = 0; c = 0;
    #pragma unroll
    for (int tt = 0; tt < 32; ++tt){
      int nf = (tt >> 2) + ((tt & 3) == 3);
      if (i >= acc2 && i < acc2 + nf){ t = tt; c = i - acc2; }
      acc2 += nf;
    }
    ns = 16;
  } else if (i < 128){ int k = i - 120; t = 4 * k + 2; c = k; ns = 12; }
  else if (i < 136)  { int k = i - 128; t = 4 * k + 1; c = k; ns = 8; }
  else               { int k = i - 136; t = 4 * k;     c = k; ns = 4; }

  const int qt0  = t * 128;
  const int kvlo = c << 9;

  const short* Qg = Q  + ((size_t)b * S_LEN + qt0 + wave * 32) * HEAD;
  const short* Kg = K  + (size_t)b * S_LEN * HEAD;
  const short* Vg = VT + (size_t)b * HEAD * S_LEN;

  bf16x8 qf[2][4];
  #pragma unroll
  for (int qs = 0; qs < 2; ++qs)
    #pragma unroll
    for (int sl = 0; sl < 4; ++sl)
      qf[qs][sl] = *(const bf16x8*)(Qg + (size_t)(qs * 16 + lr) * HEAD + sl * 32 + hg * 8);

  // wave w stages K slots {2w,2w+1} into Kl[kb] and V slots into Vl[vb]
#define ATTN_STAGE(kb, vb, j0)                                                     \
  {                                                                                \
    _Pragma("unroll")                                                              \
    for (int q = 0; q < 2; ++q){                                                   \
      int s = wave * 2 + q;                                                        \
      gload16(Kg + (size_t)((j0) + (s >> 2) * 16 + lr) * HEAD + (s & 3) * 32 + hg * 8, \
              &Kl[kb][s * 512]);                                                   \
    }                                                                              \
    _Pragma("unroll")                                                              \
    for (int q = 0; q < 2; ++q){                                                   \
      int s = wave * 2 + q;                                                        \
      gload16(Vg + (size_t)(s * 16 + lr) * S_LEN + (j0) + hg * 8,                  \
              &Vl[vb][s * 512]);                                                   \
    }                                                                              \
  }

  ATTN_STAGE(0, 0, kvlo)

  const f32x4 zero = {0.f, 0.f, 0.f, 0.f};
  f32x4 acc[8][2];
  #pragma unroll
  for (int f = 0; f < 8; ++f){ acc[f][0] = zero; acc[f][1] = zero; }
  float den[2] = {0.f, 0.f};
  bf16x8 pfp[2];               // carried P fragments (PV deferred one step)

  int kc = 0, vcur = 0;
  for (int st = 0; st < ns; ++st){
    const int j0 = kvlo + st * 32;
    const int vnxt = (vcur + 1 == 3) ? 0 : vcur + 1;
    const int vprv = (vcur == 0) ? 2 : vcur - 1;
    if (st + 1 < ns){
      ATTN_STAGE(kc ^ 1, vnxt, j0 + 32)
      asm volatile("s_waitcnt vmcnt(4)" ::: "memory");
    } else {
      asm volatile("s_waitcnt vmcnt(0)" ::: "memory");
    }
    __builtin_amdgcn_s_barrier();
    asm volatile("" ::: "memory");

    // ---- swapped QK^T(st): sc[kvs][qs] ----
    f32x4 sc[2][2];
    __builtin_amdgcn_s_setprio(1);
    #pragma unroll
    for (int kvs = 0; kvs < 2; ++kvs){
      sc[kvs][0] = zero; sc[kvs][1] = zero;
      #pragma unroll
      for (int sl = 0; sl < 4; ++sl){
        bf16x8 kf = *(const bf16x8*)&Kl[kc][(kvs * 4 + sl) * 512 + lane * 8];
        sc[kvs][0] = mfma16(kf, qf[0][sl], sc[kvs][0]);
        sc[kvs][1] = mfma16(kf, qf[1][sl], sc[kvs][1]);
      }
    }
    __builtin_amdgcn_s_setprio(0);

    // ---- deferred PV(st-1): register pfp + V from Vl[vprv]; overlaps the
    //      softmax below on the VALU pipe ----
    if (st > 0){
      __builtin_amdgcn_s_setprio(1);
      #pragma unroll
      for (int f = 0; f < 8; ++f){
        bf16x8 vf = *(const bf16x8*)&Vl[vprv][f * 512 + lane * 8];
        acc[f][0] = mfma16(vf, pfp[0], acc[f][0]);
        acc[f][1] = mfma16(vf, pfp[1], acc[f][1]);
      }
      __builtin_amdgcn_s_setprio(0);
    }

    // ---- causal mask per q-set ----
    if (j0 + 31 > qt0 + wave * 32){
      #pragma unroll
      for (int qs = 0; qs < 2; ++qs){
        int qr0 = qt0 + wave * 32 + qs * 16;
        #pragma unroll
        for (int kvs = 0; kvs < 2; ++kvs){
          int kv0 = j0 + kvs * 16 + hg * 4;
          #pragma unroll
          for (int r = 0; r < 4; ++r)
            if (kv0 + r > qr0 + lr) sc[kvs][qs][r] = -INFINITY;
        }
      }
    }

    // ---- fixed-max softmax: exp2 + packed cvt_pk bf16 ----
    s16x4 pb[2][2];
    #pragma unroll
    for (int qs = 0; qs < 2; ++qs){
      float p0[4], p1[4];
      #pragma unroll
      for (int r = 0; r < 4; ++r){
        p0[r] = __builtin_exp2f(sc[0][qs][r]);
        p1[r] = __builtin_exp2f(sc[1][qs][r]);
        den[qs] += p0[r] + p1[r];
      }
      u32x2 w0 = { cvtpk(p0[0], p0[1]), cvtpk(p0[2], p0[3]) };
      u32x2 w1 = { cvtpk(p1[0], p1[1]), cvtpk(p1[2], p1[3]) };
      pb[qs][0] = __builtin_bit_cast(s16x4, w0);
      pb[qs][1] = __builtin_bit_cast(s16x4, w1);
    }

    // ---- P writes, then pf reads into carried regs (consumed next step) ----
    #pragma unroll
    for (int qs = 0; qs < 2; ++qs){
      short* Pw = &Pl[wave][qs][0];
      *(s16x4*)(&Pw[lr * PPS + hg * 4])      = pb[qs][0];
      *(s16x4*)(&Pw[lr * PPS + 16 + hg * 4]) = pb[qs][1];
    }
    #pragma unroll
    for (int qs = 0; qs < 2; ++qs)
      pfp[qs] = *(const bf16x8*)(&Pl[wave][qs][lr * PPS + hg * 8]);

    asm volatile("" ::: "memory");
    __builtin_amdgcn_s_barrier();
    kc ^= 1; vcur = vnxt;
  }

  // ---- epilogue PV(ns-1): Vl[(ns-1)%3] intact (no staging after loop) ----
  {
    const int vprv = (vcur == 0) ? 2 : vcur - 1;
    #pragma unroll
    for (int f = 0; f < 8; ++f){
      bf16x8 vf = *(const bf16x8*)&Vl[vprv][f * 512 + lane * 8];
      acc[f][0] = mfma16(vf, pfp[0], acc[f][0]);
      acc[f][1] = mfma16(vf, pfp[1], acc[f][1]);
    }
  }

  // ---- den: one-time cross-lane reduce ----
  #pragma unroll
  for (int qs = 0; qs < 2; ++qs){
    den[qs] += __shfl_xor(den[qs], 16);
    den[qs] += __shfl_xor(den[qs], 32);
  }

  // ---- write UNNORMALIZED partials (bf16) + den (f32); item = 128 rows ----
  const int pidx = b * 144 + i;
  short* Op = Opart + (size_t)pidx * 16384;
  #pragma unroll
  for (int qs = 0; qs < 2; ++qs){
    const int rowblk = wave * 2 + qs;      // 0..7
    #pragma unroll
    for (int f = 0; f < 8; ++f){
      u32x2 pk = { cvtpk(acc[f][qs][0], acc[f][qs][1]),
                   cvtpk(acc[f][qs][2], acc[f][qs][3]) };
      *(u32x2*)(Op + (rowblk * 16 + lr) * 128 + f * 16 + hg * 4) = pk;
    }
    if (hg == 0)
      Dn[pidx * 128 + rowblk * 16 + lr] = den[qs];
  }
}

// ---------------------------------------------------------------------------
// Kernel 3: combine — plain sum of unnormalized partials (r15/r18 verified).
// ---------------------------------------------------------------------------
__global__ __launch_bounds__(512) void combine(const short* __restrict__ Opart,
    const float* __restrict__ Dn, float* __restrict__ out){
  const int bx = blockIdx.x, b = blockIdx.y;
  const int t = bx >> 1, sub = bx & 1;
  const int row = threadIdx.x >> 3;
  const int cgp = threadIdx.x & 7;
  const int rI = sub * 64 + row;           // 0..127 within tile
  const int a = t >> 2, bb = t & 3;
  const int Ffull = a * (2 * a + bb - 1);
  const int nfull = a + (bb == 3);
  const int nc = a + 1;
  const int ipart = (bb == 2) ? 120 + a : (bb == 1) ? 128 + a : 136 + a;

  float L = 0.f;
  float o[16];
  #pragma unroll
  for (int e = 0; e < 16; ++e) o[e] = 0.f;
  for (int cc = 0; cc < nc; ++cc){
    int ii = (cc < nfull) ? Ffull + cc : ipart;
    int id = b * 144 + ii;
    L += Dn[id * 128 + rI];
    const short* op = Opart + (size_t)id * 16384 + rI * 128 + cgp * 16;
    bf16x8 v0 = *(const bf16x8*)(op);
    bf16x8 v1 = *(const bf16x8*)(op + 8);
    #pragma unroll
    for (int e = 0; e < 8; ++e){
      o[e]     += bf2f(v0[e]);
      o[8 + e] += bf2f(v1[e]);
    }
  }
  float inv = 1.f / L;
  float* dst = out + ((size_t)b * S_LEN + t * 128 + rI) * HEAD + cgp * 16;
  #pragma unroll
  for (int e4 = 0; e4 < 4; ++e4){
    float4 w4 = { o[e4*4]*inv, o[e4*4+1]*inv, o[e4*4+2]*inv, o[e4*4+3]*inv };
    *(float4*)(dst + e4 * 4) = w4;
  }
}

// ---------------------------------------------------------------------------
extern "C" void kernel_launch(void* const* d_in, const int* in_sizes, int n_in,
                              void* d_out, int out_size, void* d_ws, size_t ws_size,
                              hipStream_t stream){
  const float* x  = (const float*)d_in[0];
  const float* Wq = (const float*)d_in[1];
  const float* bq = (const float*)d_in[2];
  const float* Wk = (const float*)d_in[3];
  const float* bk = (const float*)d_in[4];
  const float* Wv = (const float*)d_in[5];
  const float* bv = (const float*)d_in[6];
  float* out = (float*)d_out;

  char* ws = (char*)d_ws;
  short* WT    = (short*)(ws);                         // 768 KB
  float* bias  = (float*)(ws + 786432);                // 1.5 KB
  short* Qb    = (short*)(ws + (1u << 20));            // 4 MB
  short* Kb    = (short*)(ws + (1u << 20) + 4194304u); // 4 MB
  short* VTb   = (short*)(ws + (1u << 20) + 8388608u); // 4 MB
  short* Opart = (short*)(ws + 13631488u);             // 576*32KB = 18.9 MB
  float* Dn    = (float*)(ws + 32505856u);             // 288 KB

  prep_w<<<1536, 256, 0, stream>>>(Wq, bq, Wk, bk, Wv, bv, WT, bias);
  qkv_proj<<<256, 1024, 0, stream>>>(x, WT, bias, Qb, Kb, VTb);
  attn<<<dim3(4, 144), 256, 0, stream>>>(Qb, Kb, VTb, Opart, Dn);
  combine<<<dim3(64, 4), 512, 0, stream>>>(Opart, Dn, out);
}